// Round 1
// baseline (311.873 us; speedup 1.0000x reference)
//
#include <hip/hip_runtime.h>

// Flow1: RealNVP coupling flow. K=32 B=4096 ZS=128 ZH=64 HS=50 NF=2.
// Round 5: occupancy/latency attack.
//  - Removed the per-step block-shared LDS weight staging (wsh) entirely.
//    Weights (110 KB bf16, identical for all 1024 blocks) are L1/L2-resident;
//    B-fragments are loaded straight from global as 16B dwordx4.
//  - Zero __syncthreads() in the kernel now (zA/hA are per-wave; same-wave
//    DS in-order execution carries the phaseA->phaseB hazard, as before).
//  - LDS/block 64512 -> 36864 B (4 blocks/CU by LDS); __launch_bounds__(256,4)
//    to force <=128 VGPRs -> target 16 waves/CU (was ~4).
//  - tanh/sigmoid use v_rcp_f32 (__builtin_amdgcn_rcpf) instead of the
//    full-precision divide expansion (~1 ulp, negligible vs bf16 rounding).
//
// Layouts (m89/m91-verified):
//   A-frag: A[m][k], m=lane&15, k=quad*8+j (j=0..7) per 32-K-tile
//   B-frag: B[k][n], n=lane&15, k=quad*8+j
//   C/D   : D[m][n], n=lane&15, m=quad*4+reg

typedef unsigned short ushort_t;
typedef unsigned int   uint_t;
typedef short bf8 __attribute__((ext_vector_type(8)));
typedef float f4  __attribute__((ext_vector_type(4)));

#define KK   32
#define BB   4096
#define ZSD  128
#define ZHD  64
#define HSD  50
#define NROWS (KK*BB)

#define WST  72                   // k-stride (shorts) for weight/act tiles
#define MATS (64*WST)             // shorts per padded matrix  = 4608
#define WGL_SHORTS (12*MATS)      // 55296 shorts = 110592 B
#define WS_BYTES   (WGL_SHORTS*2 + 768*4)   // + padded fp32 biases [4][3][64]

__device__ __forceinline__ float bf2f(ushort_t u){ union{uint_t i; float f;} v; v.i = ((uint_t)u)<<16; return v.f; }
__device__ __forceinline__ ushort_t f2bf(float f){
  union{float f; uint_t i;} v; v.f = f;
  uint_t x = v.i;
  return (ushort_t)((x + 0x7fffu + ((x>>16)&1u)) >> 16);   // RNE
}

__device__ __forceinline__ float rcp_fast(float x){ return __builtin_amdgcn_rcpf(x); }

__device__ __forceinline__ float tanh_fast(float x){
  float ax = fabsf(x);
  float t  = __expf(-2.0f*ax);                  // (0,1]
  float r  = (1.0f - t) * rcp_fast(1.0f + t);
  union{float f; uint_t i;} u, s; u.f = r; s.f = x;
  u.i |= (s.i & 0x80000000u);
  return u.f;
}

__device__ __forceinline__ void sigmoid_log(float x, float& sig, float& lsig){
  float ax  = fabsf(x);
  float e   = __expf(-ax);
  float d   = 1.0f + e;
  float inv = rcp_fast(d);
  float ld  = __logf(d);
  bool pos  = (x >= 0.0f);
  sig  = pos ? inv : e*inv;
  lsig = pos ? -ld : x - ld;
}

__device__ __forceinline__ f4 MFMA(bf8 a, bf8 b, f4 c){
  return __builtin_amdgcn_mfma_f32_16x16x32_bf16(a, b, c, 0, 0, 0);
}

// ---- weight preconversion: fp32 -> padded bf16 [step][mat][n][WST] + biases
__global__ void convert_weights(const float* __restrict__ W0g,
                                const float* __restrict__ b0g,
                                const float* __restrict__ W1g,
                                const float* __restrict__ b1g,
                                const float* __restrict__ W2g,
                                const float* __restrict__ b2g,
                                ushort_t* __restrict__ wgl)
{
  int t = blockIdx.x*256 + threadIdx.x;
  if (t < WGL_SHORTS){
    int mi  = t / MATS;             // step*3 + which
    int rem = t % MATS;
    int n   = rem / WST;
    int k   = rem % WST;
    int step  = mi / 3;
    int which = mi % 3;
    float v = 0.0f;
    if (which == 0){                           // B0[k=z][n=h] = W0[step][n][k]
      if (n < HSD && k < ZHD) v = W0g[(step*HSD + n)*ZHD + k];
    } else if (which == 1){                    // B1[k=h][n=z] = W1[step][n][k]
      if (k < HSD)            v = W1g[(step*ZHD + n)*HSD + k];
    } else {
      if (k < HSD)            v = W2g[(step*ZHD + n)*HSD + k];
    }
    wgl[t] = f2bf(v);
  }
  if (t < 768){                                // biases fp32 padded to 64
    float* bp = (float*)(wgl + WGL_SHORTS);
    int step  = t / 192;
    int rem   = t % 192;
    int which = rem / 64;
    int n     = rem % 64;
    float v = 0.0f;
    if (which == 0){ if (n < HSD) v = b0g[step*HSD + n]; }
    else if (which == 1) v = b1g[step*ZHD + n];
    else                 v = b2g[step*ZHD + n];
    bp[t] = v;
  }
}

// one coupling step; pz = passive-half registers (updated), active already in zAw
__device__ __forceinline__ void do_step(
    int s, float (&pz)[2][16], float (&T)[2][4],
    ushort_t* zAw, ushort_t* hAw,
    const ushort_t* wgl, const float* wsb,
    int quad, int l15, int wr)
{
  // this step's 3 matrices, read directly from global (L1/L2-resident)
  const ushort_t* ws = wgl + (size_t)(s*3)*MATS;

  // ---- phase A: H = tanh(Zact @ B0 + b0) ----
  bf8 zf[2][2];
  #pragma unroll
  for (int m=0;m<2;++m)
    #pragma unroll
    for (int kt=0;kt<2;++kt)
      zf[m][kt] = *(const bf8*)(zAw + (m*16 + l15)*WST + kt*32 + quad*8);

  #pragma unroll
  for (int nt=0;nt<4;++nt){
    const ushort_t* wb = ws + (0*64 + nt*16 + l15)*WST + quad*8;
    bf8 w0a = *(const bf8*)(wb);
    bf8 w0b = *(const bf8*)(wb + 32);
    float b0v = wsb[(s*3+0)*64 + nt*16 + l15];
    #pragma unroll
    for (int m=0;m<2;++m){
      f4 acc = {0.f,0.f,0.f,0.f};
      acc = MFMA(zf[m][0], w0a, acc);
      acc = MFMA(zf[m][1], w0b, acc);
      #pragma unroll
      for (int i=0;i<4;++i){
        float h = tanh_fast(acc[i] + b0v);
        hAw[(m*16 + quad*4 + i)*WST + nt*16 + l15] = f2bf(h);
      }
    }
  }

  // ---- phase B: MEW = H@B1 + b1 ; SIG = sigmoid(H@B2 + b2) ----
  bf8 hf[2][2];
  #pragma unroll
  for (int m=0;m<2;++m)
    #pragma unroll
    for (int kt=0;kt<2;++kt)
      hf[m][kt] = *(const bf8*)(hAw + (m*16 + l15)*WST + kt*32 + quad*8);

  #pragma unroll
  for (int nt=0;nt<4;++nt){
    const ushort_t* w1p = ws + (1*64 + nt*16 + l15)*WST + quad*8;
    const ushort_t* w2p = ws + (2*64 + nt*16 + l15)*WST + quad*8;
    bf8 w1a = *(const bf8*)(w1p);
    bf8 w1b = *(const bf8*)(w1p + 32);
    bf8 w2a = *(const bf8*)(w2p);
    bf8 w2b = *(const bf8*)(w2p + 32);
    float b1v = wsb[(s*3+1)*64 + nt*16 + l15];
    float b2v = wsb[(s*3+2)*64 + nt*16 + l15];
    #pragma unroll
    for (int m=0;m<2;++m){
      f4 am = {0.f,0.f,0.f,0.f};
      f4 as = {0.f,0.f,0.f,0.f};
      am = MFMA(hf[m][0], w1a, am);
      am = MFMA(hf[m][1], w1b, am);
      as = MFMA(hf[m][0], w2a, as);
      as = MFMA(hf[m][1], w2b, as);
      #pragma unroll
      for (int i=0;i<4;++i){
        float mew  = am[i] + b1v;
        float spre = as[i] + b2v;
        float sig, lsig;
        sigmoid_log(spre, sig, lsig);
        pz[m][nt*4+i] = fmaf(pz[m][nt*4+i], sig, mew);
        T[m][i] += lsig;
      }
    }
  }

  // new active = just-updated passive -> zA (bf16, A-layout)
  if (wr){
    #pragma unroll
    for (int m=0;m<2;++m)
      #pragma unroll
      for (int nt=0;nt<4;++nt)
        #pragma unroll
        for (int i=0;i<4;++i)
          zAw[(m*16 + quad*4 + i)*WST + nt*16 + l15] = f2bf(pz[m][nt*4+i]);
  }
}

__global__ __launch_bounds__(256, 4) void flow_mfma(
    const float* __restrict__ mean, const float* __restrict__ logvar,
    const float* __restrict__ eps,
    const ushort_t* __restrict__ wgl,
    float* __restrict__ out)
{
  __shared__ __align__(16) ushort_t zA[4][32*WST];      // 4 x 4608 B
  __shared__ __align__(16) ushort_t hA[4][32*WST];      // 4 x 4608 B

  const int tid  = threadIdx.x;
  const int wave = tid >> 6;
  const int lane = tid & 63;
  const int quad = lane >> 4;
  const int l15  = lane & 15;
  const int rbase = blockIdx.x*128 + wave*32;

  const float* wsb = (const float*)(wgl + WGL_SHORTS);
  ushort_t* zAw = zA[wave];
  ushort_t* hAw = hA[wave];

  // z1D/z2D in C/D layout: [mtile][nt*4+reg] -> row=mtile*16+quad*4+reg,
  // col(z-index within half)=nt*16+l15
  float z1D[2][16], z2D[2][16];
  float T[2][4];                     // T = 0.5*sum(lv+eps^2) + sum(lsig)

  // ---- init: z = eps*exp(0.5*lv)+mean, loaded directly in D-layout ----
  #pragma unroll
  for (int m=0;m<2;++m){
    #pragma unroll
    for (int i=0;i<4;++i){
      int rrow = rbase + m*16 + quad*4 + i;
      int brow = rrow & (BB-1);
      const float* er = eps    + (size_t)rrow*ZSD;
      const float* mr = mean   + (size_t)brow*ZSD;
      const float* vr = logvar + (size_t)brow*ZSD;
      float acc = 0.f;
      #pragma unroll
      for (int nt=0;nt<4;++nt){
        int c1 = nt*16 + l15;
        int c2 = 64 + c1;
        float e1 = er[c1], v1 = vr[c1], m1 = mr[c1];
        float e2 = er[c2], v2 = vr[c2], m2 = mr[c2];
        z1D[m][nt*4+i] = fmaf(e1, __expf(0.5f*v1), m1);
        z2D[m][nt*4+i] = fmaf(e2, __expf(0.5f*v2), m2);
        acc += (v1 + e1*e1) + (v2 + e2*e2);
      }
      T[m][i] = 0.5f*acc;
    }
  }

  // initial active = z1 -> zA
  #pragma unroll
  for (int m=0;m<2;++m)
    #pragma unroll
    for (int nt=0;nt<4;++nt)
      #pragma unroll
      for (int i=0;i<4;++i)
        zAw[(m*16 + quad*4 + i)*WST + nt*16 + l15] = f2bf(z1D[m][nt*4+i]);

  // ---- 4 coupling steps (2 bodies in a non-unrolled loop to bound I$) ----
  #pragma unroll 1
  for (int it=0; it<2; ++it){
    do_step(2*it+0, z2D, T, zAw, hAw, wgl, wsb, quad, l15, 1);
    do_step(2*it+1, z1D, T, zAw, hAw, wgl, wsb, quad, l15, it==0);
  }

  // ---- store z_out (fp32) ----
  #pragma unroll
  for (int m=0;m<2;++m){
    #pragma unroll
    for (int i=0;i<4;++i){
      int rrow = rbase + m*16 + quad*4 + i;
      float* orow = out + (size_t)rrow*ZSD;
      #pragma unroll
      for (int nt=0;nt<4;++nt){
        orow[nt*16 + l15]      = z1D[m][nt*4+i];
        orow[64 + nt*16 + l15] = z2D[m][nt*4+i];
      }
    }
  }

  // ---- logpz = -0.5*128*ln(2pi) - T_rowsum ; reduce T across the 16 lanes
  // of each quad (they cover all 128 cols of rows quad*4+reg) ----
  #pragma unroll
  for (int m=0;m<2;++m)
    #pragma unroll
    for (int i=0;i<4;++i){
      float v = T[m][i];
      v += __shfl_xor(v, 1, 64);
      v += __shfl_xor(v, 2, 64);
      v += __shfl_xor(v, 4, 64);
      v += __shfl_xor(v, 8, 64);
      T[m][i] = v;
    }
  if (l15 == 0){
    const float NC = -0.5f * 128.0f * 1.8378770664093453f;
    #pragma unroll
    for (int m=0;m<2;++m)
      #pragma unroll
      for (int i=0;i<4;++i){
        int rrow = rbase + m*16 + quad*4 + i;
        out[(size_t)NROWS*ZSD + rrow] = NC - T[m][i];
      }
  }
}

extern "C" void kernel_launch(void* const* d_in, const int* in_sizes, int n_in,
                              void* d_out, int out_size, void* d_ws, size_t ws_size,
                              hipStream_t stream)
{
  const float* mean   = (const float*)d_in[0];
  const float* logvar = (const float*)d_in[1];
  const float* eps    = (const float*)d_in[2];
  const float* W0     = (const float*)d_in[3];
  const float* b0     = (const float*)d_in[4];
  const float* W1     = (const float*)d_in[5];
  const float* b1     = (const float*)d_in[6];
  const float* W2     = (const float*)d_in[7];
  const float* b2     = (const float*)d_in[8];
  ushort_t* wgl = (ushort_t*)d_ws;          // ws_size >= 156448 proven round 3

  convert_weights<<<(WGL_SHORTS + 255)/256, 256, 0, stream>>>(W0,b0,W1,b1,W2,b2, wgl);
  flow_mfma<<<NROWS/128, 256, 0, stream>>>(mean, logvar, eps, wgl, (float*)d_out);
}

// Round 2
// 286.300 us; speedup vs baseline: 1.0893x; 1.0893x over previous
//
#include <hip/hip_runtime.h>

// Flow1: RealNVP coupling flow. K=32 B=4096 ZS=128 ZH=64 HS=50 NF=2.
// Round 6: fix round-5 spill. Round 5 removed the per-step LDS weight staging
// and all __syncthreads() (good), but __launch_bounds__(256,4) over-squeezed
// VGPRs to 64 -> ~500 MB of scratch spill traffic (WRITE_SIZE 437 MB vs 67 MB
// ideal). This round: __launch_bounds__(256,3) -> VGPR cap 170 (round 4 fit
// the same live state in 160), zero spill, 3 waves/SIMD = 12 waves/CU.
//  - Weights read straight from global (L1/L2-resident, 110 KB total).
//  - Zero barriers: zA/hA are per-wave, same-wave DS ordering carries the
//    phaseA->phaseB hazard.
//  - LDS/block 36864 B (not the limiter at 3 blocks/CU).
//
// Layouts (m89/m91-verified):
//   A-frag: A[m][k], m=lane&15, k=quad*8+j (j=0..7) per 32-K-tile
//   B-frag: B[k][n], n=lane&15, k=quad*8+j
//   C/D   : D[m][n], n=lane&15, m=quad*4+reg

typedef unsigned short ushort_t;
typedef unsigned int   uint_t;
typedef short bf8 __attribute__((ext_vector_type(8)));
typedef float f4  __attribute__((ext_vector_type(4)));

#define KK   32
#define BB   4096
#define ZSD  128
#define ZHD  64
#define HSD  50
#define NROWS (KK*BB)

#define WST  72                   // k-stride (shorts) for weight/act tiles
#define MATS (64*WST)             // shorts per padded matrix  = 4608
#define WGL_SHORTS (12*MATS)      // 55296 shorts = 110592 B
#define WS_BYTES   (WGL_SHORTS*2 + 768*4)   // + padded fp32 biases [4][3][64]

__device__ __forceinline__ float bf2f(ushort_t u){ union{uint_t i; float f;} v; v.i = ((uint_t)u)<<16; return v.f; }
__device__ __forceinline__ ushort_t f2bf(float f){
  union{float f; uint_t i;} v; v.f = f;
  uint_t x = v.i;
  return (ushort_t)((x + 0x7fffu + ((x>>16)&1u)) >> 16);   // RNE
}

__device__ __forceinline__ float rcp_fast(float x){ return __builtin_amdgcn_rcpf(x); }

__device__ __forceinline__ float tanh_fast(float x){
  float ax = fabsf(x);
  float t  = __expf(-2.0f*ax);                  // (0,1]
  float r  = (1.0f - t) * rcp_fast(1.0f + t);
  union{float f; uint_t i;} u, s; u.f = r; s.f = x;
  u.i |= (s.i & 0x80000000u);
  return u.f;
}

__device__ __forceinline__ void sigmoid_log(float x, float& sig, float& lsig){
  float ax  = fabsf(x);
  float e   = __expf(-ax);
  float d   = 1.0f + e;
  float inv = rcp_fast(d);
  float ld  = __logf(d);
  bool pos  = (x >= 0.0f);
  sig  = pos ? inv : e*inv;
  lsig = pos ? -ld : x - ld;
}

__device__ __forceinline__ f4 MFMA(bf8 a, bf8 b, f4 c){
  return __builtin_amdgcn_mfma_f32_16x16x32_bf16(a, b, c, 0, 0, 0);
}

// ---- weight preconversion: fp32 -> padded bf16 [step][mat][n][WST] + biases
__global__ void convert_weights(const float* __restrict__ W0g,
                                const float* __restrict__ b0g,
                                const float* __restrict__ W1g,
                                const float* __restrict__ b1g,
                                const float* __restrict__ W2g,
                                const float* __restrict__ b2g,
                                ushort_t* __restrict__ wgl)
{
  int t = blockIdx.x*256 + threadIdx.x;
  if (t < WGL_SHORTS){
    int mi  = t / MATS;             // step*3 + which
    int rem = t % MATS;
    int n   = rem / WST;
    int k   = rem % WST;
    int step  = mi / 3;
    int which = mi % 3;
    float v = 0.0f;
    if (which == 0){                           // B0[k=z][n=h] = W0[step][n][k]
      if (n < HSD && k < ZHD) v = W0g[(step*HSD + n)*ZHD + k];
    } else if (which == 1){                    // B1[k=h][n=z] = W1[step][n][k]
      if (k < HSD)            v = W1g[(step*ZHD + n)*HSD + k];
    } else {
      if (k < HSD)            v = W2g[(step*ZHD + n)*HSD + k];
    }
    wgl[t] = f2bf(v);
  }
  if (t < 768){                                // biases fp32 padded to 64
    float* bp = (float*)(wgl + WGL_SHORTS);
    int step  = t / 192;
    int rem   = t % 192;
    int which = rem / 64;
    int n     = rem % 64;
    float v = 0.0f;
    if (which == 0){ if (n < HSD) v = b0g[step*HSD + n]; }
    else if (which == 1) v = b1g[step*ZHD + n];
    else                 v = b2g[step*ZHD + n];
    bp[t] = v;
  }
}

// one coupling step; pz = passive-half registers (updated), active already in zAw
__device__ __forceinline__ void do_step(
    int s, float (&pz)[2][16], float (&T)[2][4],
    ushort_t* zAw, ushort_t* hAw,
    const ushort_t* wgl, const float* wsb,
    int quad, int l15, int wr)
{
  // this step's 3 matrices, read directly from global (L1/L2-resident)
  const ushort_t* ws = wgl + (size_t)(s*3)*MATS;

  // ---- phase A: H = tanh(Zact @ B0 + b0) ----
  bf8 zf[2][2];
  #pragma unroll
  for (int m=0;m<2;++m)
    #pragma unroll
    for (int kt=0;kt<2;++kt)
      zf[m][kt] = *(const bf8*)(zAw + (m*16 + l15)*WST + kt*32 + quad*8);

  #pragma unroll
  for (int nt=0;nt<4;++nt){
    const ushort_t* wb = ws + (0*64 + nt*16 + l15)*WST + quad*8;
    bf8 w0a = *(const bf8*)(wb);
    bf8 w0b = *(const bf8*)(wb + 32);
    float b0v = wsb[(s*3+0)*64 + nt*16 + l15];
    #pragma unroll
    for (int m=0;m<2;++m){
      f4 acc = {0.f,0.f,0.f,0.f};
      acc = MFMA(zf[m][0], w0a, acc);
      acc = MFMA(zf[m][1], w0b, acc);
      #pragma unroll
      for (int i=0;i<4;++i){
        float h = tanh_fast(acc[i] + b0v);
        hAw[(m*16 + quad*4 + i)*WST + nt*16 + l15] = f2bf(h);
      }
    }
  }

  // ---- phase B: MEW = H@B1 + b1 ; SIG = sigmoid(H@B2 + b2) ----
  bf8 hf[2][2];
  #pragma unroll
  for (int m=0;m<2;++m)
    #pragma unroll
    for (int kt=0;kt<2;++kt)
      hf[m][kt] = *(const bf8*)(hAw + (m*16 + l15)*WST + kt*32 + quad*8);

  #pragma unroll
  for (int nt=0;nt<4;++nt){
    const ushort_t* w1p = ws + (1*64 + nt*16 + l15)*WST + quad*8;
    const ushort_t* w2p = ws + (2*64 + nt*16 + l15)*WST + quad*8;
    bf8 w1a = *(const bf8*)(w1p);
    bf8 w1b = *(const bf8*)(w1p + 32);
    bf8 w2a = *(const bf8*)(w2p);
    bf8 w2b = *(const bf8*)(w2p + 32);
    float b1v = wsb[(s*3+1)*64 + nt*16 + l15];
    float b2v = wsb[(s*3+2)*64 + nt*16 + l15];
    #pragma unroll
    for (int m=0;m<2;++m){
      f4 am = {0.f,0.f,0.f,0.f};
      f4 as = {0.f,0.f,0.f,0.f};
      am = MFMA(hf[m][0], w1a, am);
      am = MFMA(hf[m][1], w1b, am);
      as = MFMA(hf[m][0], w2a, as);
      as = MFMA(hf[m][1], w2b, as);
      #pragma unroll
      for (int i=0;i<4;++i){
        float mew  = am[i] + b1v;
        float spre = as[i] + b2v;
        float sig, lsig;
        sigmoid_log(spre, sig, lsig);
        pz[m][nt*4+i] = fmaf(pz[m][nt*4+i], sig, mew);
        T[m][i] += lsig;
      }
    }
  }

  // new active = just-updated passive -> zA (bf16, A-layout)
  if (wr){
    #pragma unroll
    for (int m=0;m<2;++m)
      #pragma unroll
      for (int nt=0;nt<4;++nt)
        #pragma unroll
        for (int i=0;i<4;++i)
          zAw[(m*16 + quad*4 + i)*WST + nt*16 + l15] = f2bf(pz[m][nt*4+i]);
  }
}

__global__ __launch_bounds__(256, 3) void flow_mfma(
    const float* __restrict__ mean, const float* __restrict__ logvar,
    const float* __restrict__ eps,
    const ushort_t* __restrict__ wgl,
    float* __restrict__ out)
{
  __shared__ __align__(16) ushort_t zA[4][32*WST];      // 4 x 4608 B
  __shared__ __align__(16) ushort_t hA[4][32*WST];      // 4 x 4608 B

  const int tid  = threadIdx.x;
  const int wave = tid >> 6;
  const int lane = tid & 63;
  const int quad = lane >> 4;
  const int l15  = lane & 15;
  const int rbase = blockIdx.x*128 + wave*32;

  const float* wsb = (const float*)(wgl + WGL_SHORTS);
  ushort_t* zAw = zA[wave];
  ushort_t* hAw = hA[wave];

  // z1D/z2D in C/D layout: [mtile][nt*4+reg] -> row=mtile*16+quad*4+reg,
  // col(z-index within half)=nt*16+l15
  float z1D[2][16], z2D[2][16];
  float T[2][4];                     // T = 0.5*sum(lv+eps^2) + sum(lsig)

  // ---- init: z = eps*exp(0.5*lv)+mean, loaded directly in D-layout ----
  #pragma unroll
  for (int m=0;m<2;++m){
    #pragma unroll
    for (int i=0;i<4;++i){
      int rrow = rbase + m*16 + quad*4 + i;
      int brow = rrow & (BB-1);
      const float* er = eps    + (size_t)rrow*ZSD;
      const float* mr = mean   + (size_t)brow*ZSD;
      const float* vr = logvar + (size_t)brow*ZSD;
      float acc = 0.f;
      #pragma unroll
      for (int nt=0;nt<4;++nt){
        int c1 = nt*16 + l15;
        int c2 = 64 + c1;
        float e1 = er[c1], v1 = vr[c1], m1 = mr[c1];
        float e2 = er[c2], v2 = vr[c2], m2 = mr[c2];
        z1D[m][nt*4+i] = fmaf(e1, __expf(0.5f*v1), m1);
        z2D[m][nt*4+i] = fmaf(e2, __expf(0.5f*v2), m2);
        acc += (v1 + e1*e1) + (v2 + e2*e2);
      }
      T[m][i] = 0.5f*acc;
    }
  }

  // initial active = z1 -> zA
  #pragma unroll
  for (int m=0;m<2;++m)
    #pragma unroll
    for (int nt=0;nt<4;++nt)
      #pragma unroll
      for (int i=0;i<4;++i)
        zAw[(m*16 + quad*4 + i)*WST + nt*16 + l15] = f2bf(z1D[m][nt*4+i]);

  // ---- 4 coupling steps (2 bodies in a non-unrolled loop to bound I$) ----
  #pragma unroll 1
  for (int it=0; it<2; ++it){
    do_step(2*it+0, z2D, T, zAw, hAw, wgl, wsb, quad, l15, 1);
    do_step(2*it+1, z1D, T, zAw, hAw, wgl, wsb, quad, l15, it==0);
  }

  // ---- store z_out (fp32) ----
  #pragma unroll
  for (int m=0;m<2;++m){
    #pragma unroll
    for (int i=0;i<4;++i){
      int rrow = rbase + m*16 + quad*4 + i;
      float* orow = out + (size_t)rrow*ZSD;
      #pragma unroll
      for (int nt=0;nt<4;++nt){
        orow[nt*16 + l15]      = z1D[m][nt*4+i];
        orow[64 + nt*16 + l15] = z2D[m][nt*4+i];
      }
    }
  }

  // ---- logpz = -0.5*128*ln(2pi) - T_rowsum ; reduce T across the 16 lanes
  // of each quad (they cover all 128 cols of rows quad*4+reg) ----
  #pragma unroll
  for (int m=0;m<2;++m)
    #pragma unroll
    for (int i=0;i<4;++i){
      float v = T[m][i];
      v += __shfl_xor(v, 1, 64);
      v += __shfl_xor(v, 2, 64);
      v += __shfl_xor(v, 4, 64);
      v += __shfl_xor(v, 8, 64);
      T[m][i] = v;
    }
  if (l15 == 0){
    const float NC = -0.5f * 128.0f * 1.8378770664093453f;
    #pragma unroll
    for (int m=0;m<2;++m)
      #pragma unroll
      for (int i=0;i<4;++i){
        int rrow = rbase + m*16 + quad*4 + i;
        out[(size_t)NROWS*ZSD + rrow] = NC - T[m][i];
      }
  }
}

extern "C" void kernel_launch(void* const* d_in, const int* in_sizes, int n_in,
                              void* d_out, int out_size, void* d_ws, size_t ws_size,
                              hipStream_t stream)
{
  const float* mean   = (const float*)d_in[0];
  const float* logvar = (const float*)d_in[1];
  const float* eps    = (const float*)d_in[2];
  const float* W0     = (const float*)d_in[3];
  const float* b0     = (const float*)d_in[4];
  const float* W1     = (const float*)d_in[5];
  const float* b1     = (const float*)d_in[6];
  const float* W2     = (const float*)d_in[7];
  const float* b2     = (const float*)d_in[8];
  ushort_t* wgl = (ushort_t*)d_ws;          // ws_size >= 156448 proven round 3

  convert_weights<<<(WGL_SHORTS + 255)/256, 256, 0, stream>>>(W0,b0,W1,b1,W2,b2, wgl);
  flow_mfma<<<NROWS/128, 256, 0, stream>>>(mean, logvar, eps, wgl, (float*)d_out);
}

// Round 3
// 190.776 us; speedup vs baseline: 1.6348x; 1.5007x over previous
//
#include <hip/hip_runtime.h>

// Flow1: RealNVP coupling flow. K=32 B=4096 ZS=128 ZH=64 HS=50 NF=2.
// Round 7: kill the spill by shrinking live state, not by forcing bounds.
// Evidence: launch_bounds(256,4)->64 arch VGPR, (256,3)->84 arch VGPR — the
// compiler gives ~half the per-wave budget to the AGPR block when a waves-
// per-EU bound is set, and the ~140-float live state then spills (~290 MB of
// scratch traffic at round 6). Fix: 16 rows/wave (1 M-tile) instead of 32.
// Live state ~= 32 (z-regs) + 4 (T) + frags ~ 100 VGPR -> fits the default
// budget with NO min-waves bound. Grid 2048 blocks; LDS 18432 B/block.
//  - Weights read straight from global (L1/L2-resident, 110 KB total).
//  - Zero barriers: zA/hA per-wave; same-wave DS ordering carries hazards.
//
// Layouts (m89/m91-verified):
//   A-frag: A[m][k], m=lane&15, k=quad*8+j (j=0..7) per 32-K-tile
//   B-frag: B[k][n], n=lane&15, k=quad*8+j
//   C/D   : D[m][n], n=lane&15, m=quad*4+reg

typedef unsigned short ushort_t;
typedef unsigned int   uint_t;
typedef short bf8 __attribute__((ext_vector_type(8)));
typedef float f4  __attribute__((ext_vector_type(4)));

#define KK   32
#define BB   4096
#define ZSD  128
#define ZHD  64
#define HSD  50
#define NROWS (KK*BB)

#define WST  72                   // k-stride (shorts) for weight/act tiles
#define MATS (64*WST)             // shorts per padded matrix  = 4608
#define WGL_SHORTS (12*MATS)      // 55296 shorts = 110592 B
#define WS_BYTES   (WGL_SHORTS*2 + 768*4)   // + padded fp32 biases [4][3][64]

__device__ __forceinline__ float bf2f(ushort_t u){ union{uint_t i; float f;} v; v.i = ((uint_t)u)<<16; return v.f; }
__device__ __forceinline__ ushort_t f2bf(float f){
  union{float f; uint_t i;} v; v.f = f;
  uint_t x = v.i;
  return (ushort_t)((x + 0x7fffu + ((x>>16)&1u)) >> 16);   // RNE
}

__device__ __forceinline__ float rcp_fast(float x){ return __builtin_amdgcn_rcpf(x); }

__device__ __forceinline__ float tanh_fast(float x){
  float ax = fabsf(x);
  float t  = __expf(-2.0f*ax);                  // (0,1]
  float r  = (1.0f - t) * rcp_fast(1.0f + t);
  union{float f; uint_t i;} u, s; u.f = r; s.f = x;
  u.i |= (s.i & 0x80000000u);
  return u.f;
}

__device__ __forceinline__ void sigmoid_log(float x, float& sig, float& lsig){
  float ax  = fabsf(x);
  float e   = __expf(-ax);
  float d   = 1.0f + e;
  float inv = rcp_fast(d);
  float ld  = __logf(d);
  bool pos  = (x >= 0.0f);
  sig  = pos ? inv : e*inv;
  lsig = pos ? -ld : x - ld;
}

__device__ __forceinline__ f4 MFMA(bf8 a, bf8 b, f4 c){
  return __builtin_amdgcn_mfma_f32_16x16x32_bf16(a, b, c, 0, 0, 0);
}

// ---- weight preconversion: fp32 -> padded bf16 [step][mat][n][WST] + biases
__global__ void convert_weights(const float* __restrict__ W0g,
                                const float* __restrict__ b0g,
                                const float* __restrict__ W1g,
                                const float* __restrict__ b1g,
                                const float* __restrict__ W2g,
                                const float* __restrict__ b2g,
                                ushort_t* __restrict__ wgl)
{
  int t = blockIdx.x*256 + threadIdx.x;
  if (t < WGL_SHORTS){
    int mi  = t / MATS;             // step*3 + which
    int rem = t % MATS;
    int n   = rem / WST;
    int k   = rem % WST;
    int step  = mi / 3;
    int which = mi % 3;
    float v = 0.0f;
    if (which == 0){                           // B0[k=z][n=h] = W0[step][n][k]
      if (n < HSD && k < ZHD) v = W0g[(step*HSD + n)*ZHD + k];
    } else if (which == 1){                    // B1[k=h][n=z] = W1[step][n][k]
      if (k < HSD)            v = W1g[(step*ZHD + n)*HSD + k];
    } else {
      if (k < HSD)            v = W2g[(step*ZHD + n)*HSD + k];
    }
    wgl[t] = f2bf(v);
  }
  if (t < 768){                                // biases fp32 padded to 64
    float* bp = (float*)(wgl + WGL_SHORTS);
    int step  = t / 192;
    int rem   = t % 192;
    int which = rem / 64;
    int n     = rem % 64;
    float v = 0.0f;
    if (which == 0){ if (n < HSD) v = b0g[step*HSD + n]; }
    else if (which == 1) v = b1g[step*ZHD + n];
    else                 v = b2g[step*ZHD + n];
    bp[t] = v;
  }
}

// one coupling step; pz = passive-half registers (updated), active already in zAw
__device__ __forceinline__ void do_step(
    int s, float (&pz)[16], float (&T)[4],
    ushort_t* zAw, ushort_t* hAw,
    const ushort_t* wgl, const float* wsb,
    int quad, int l15, int wr)
{
  // this step's 3 matrices, read directly from global (L1/L2-resident)
  const ushort_t* ws = wgl + (size_t)(s*3)*MATS;

  // ---- phase A: H = tanh(Zact @ B0 + b0) ----
  bf8 zf[2];
  #pragma unroll
  for (int kt=0;kt<2;++kt)
    zf[kt] = *(const bf8*)(zAw + l15*WST + kt*32 + quad*8);

  #pragma unroll
  for (int nt=0;nt<4;++nt){
    const ushort_t* wb = ws + (0*64 + nt*16 + l15)*WST + quad*8;
    bf8 w0a = *(const bf8*)(wb);
    bf8 w0b = *(const bf8*)(wb + 32);
    float b0v = wsb[(s*3+0)*64 + nt*16 + l15];
    f4 acc = {0.f,0.f,0.f,0.f};
    acc = MFMA(zf[0], w0a, acc);
    acc = MFMA(zf[1], w0b, acc);
    #pragma unroll
    for (int i=0;i<4;++i){
      float h = tanh_fast(acc[i] + b0v);
      hAw[(quad*4 + i)*WST + nt*16 + l15] = f2bf(h);
    }
  }

  // ---- phase B: MEW = H@B1 + b1 ; SIG = sigmoid(H@B2 + b2) ----
  bf8 hf[2];
  #pragma unroll
  for (int kt=0;kt<2;++kt)
    hf[kt] = *(const bf8*)(hAw + l15*WST + kt*32 + quad*8);

  #pragma unroll
  for (int nt=0;nt<4;++nt){
    const ushort_t* w1p = ws + (1*64 + nt*16 + l15)*WST + quad*8;
    const ushort_t* w2p = ws + (2*64 + nt*16 + l15)*WST + quad*8;
    bf8 w1a = *(const bf8*)(w1p);
    bf8 w1b = *(const bf8*)(w1p + 32);
    bf8 w2a = *(const bf8*)(w2p);
    bf8 w2b = *(const bf8*)(w2p + 32);
    float b1v = wsb[(s*3+1)*64 + nt*16 + l15];
    float b2v = wsb[(s*3+2)*64 + nt*16 + l15];
    f4 am = {0.f,0.f,0.f,0.f};
    f4 as = {0.f,0.f,0.f,0.f};
    am = MFMA(hf[0], w1a, am);
    am = MFMA(hf[1], w1b, am);
    as = MFMA(hf[0], w2a, as);
    as = MFMA(hf[1], w2b, as);
    #pragma unroll
    for (int i=0;i<4;++i){
      float mew  = am[i] + b1v;
      float spre = as[i] + b2v;
      float sig, lsig;
      sigmoid_log(spre, sig, lsig);
      pz[nt*4+i] = fmaf(pz[nt*4+i], sig, mew);
      T[i] += lsig;
    }
  }

  // new active = just-updated passive -> zA (bf16, A-layout)
  if (wr){
    #pragma unroll
    for (int nt=0;nt<4;++nt)
      #pragma unroll
      for (int i=0;i<4;++i)
        zAw[(quad*4 + i)*WST + nt*16 + l15] = f2bf(pz[nt*4+i]);
  }
}

__global__ __launch_bounds__(256) void flow_mfma(
    const float* __restrict__ mean, const float* __restrict__ logvar,
    const float* __restrict__ eps,
    const ushort_t* __restrict__ wgl,
    float* __restrict__ out)
{
  __shared__ __align__(16) ushort_t zA[4][16*WST];      // 4 x 2304 B
  __shared__ __align__(16) ushort_t hA[4][16*WST];      // 4 x 2304 B

  const int tid  = threadIdx.x;
  const int wave = tid >> 6;
  const int lane = tid & 63;
  const int quad = lane >> 4;
  const int l15  = lane & 15;
  const int rbase = blockIdx.x*64 + wave*16;

  const float* wsb = (const float*)(wgl + WGL_SHORTS);
  ushort_t* zAw = zA[wave];
  ushort_t* hAw = hA[wave];

  // z1D/z2D in C/D layout: [nt*4+reg] -> row=quad*4+reg,
  // col(z-index within half)=nt*16+l15
  float z1D[16], z2D[16];
  float T[4];                        // T = 0.5*sum(lv+eps^2) + sum(lsig)

  // ---- init: z = eps*exp(0.5*lv)+mean, loaded directly in D-layout ----
  #pragma unroll
  for (int i=0;i<4;++i){
    int rrow = rbase + quad*4 + i;
    int brow = rrow & (BB-1);
    const float* er = eps    + (size_t)rrow*ZSD;
    const float* mr = mean   + (size_t)brow*ZSD;
    const float* vr = logvar + (size_t)brow*ZSD;
    float acc = 0.f;
    #pragma unroll
    for (int nt=0;nt<4;++nt){
      int c1 = nt*16 + l15;
      int c2 = 64 + c1;
      float e1 = er[c1], v1 = vr[c1], m1 = mr[c1];
      float e2 = er[c2], v2 = vr[c2], m2 = mr[c2];
      z1D[nt*4+i] = fmaf(e1, __expf(0.5f*v1), m1);
      z2D[nt*4+i] = fmaf(e2, __expf(0.5f*v2), m2);
      acc += (v1 + e1*e1) + (v2 + e2*e2);
    }
    T[i] = 0.5f*acc;
  }

  // initial active = z1 -> zA
  #pragma unroll
  for (int nt=0;nt<4;++nt)
    #pragma unroll
    for (int i=0;i<4;++i)
      zAw[(quad*4 + i)*WST + nt*16 + l15] = f2bf(z1D[nt*4+i]);

  // ---- 4 coupling steps (2 bodies in a non-unrolled loop to bound I$) ----
  #pragma unroll 1
  for (int it=0; it<2; ++it){
    do_step(2*it+0, z2D, T, zAw, hAw, wgl, wsb, quad, l15, 1);
    do_step(2*it+1, z1D, T, zAw, hAw, wgl, wsb, quad, l15, it==0);
  }

  // ---- store z_out (fp32) ----
  #pragma unroll
  for (int i=0;i<4;++i){
    int rrow = rbase + quad*4 + i;
    float* orow = out + (size_t)rrow*ZSD;
    #pragma unroll
    for (int nt=0;nt<4;++nt){
      orow[nt*16 + l15]      = z1D[nt*4+i];
      orow[64 + nt*16 + l15] = z2D[nt*4+i];
    }
  }

  // ---- logpz = -0.5*128*ln(2pi) - T_rowsum ; reduce T across the 16 lanes
  // of each quad (they cover all 128 cols of rows quad*4+reg) ----
  #pragma unroll
  for (int i=0;i<4;++i){
    float v = T[i];
    v += __shfl_xor(v, 1, 64);
    v += __shfl_xor(v, 2, 64);
    v += __shfl_xor(v, 4, 64);
    v += __shfl_xor(v, 8, 64);
    T[i] = v;
  }
  if (l15 == 0){
    const float NC = -0.5f * 128.0f * 1.8378770664093453f;
    #pragma unroll
    for (int i=0;i<4;++i){
      int rrow = rbase + quad*4 + i;
      out[(size_t)NROWS*ZSD + rrow] = NC - T[i];
    }
  }
}

extern "C" void kernel_launch(void* const* d_in, const int* in_sizes, int n_in,
                              void* d_out, int out_size, void* d_ws, size_t ws_size,
                              hipStream_t stream)
{
  const float* mean   = (const float*)d_in[0];
  const float* logvar = (const float*)d_in[1];
  const float* eps    = (const float*)d_in[2];
  const float* W0     = (const float*)d_in[3];
  const float* b0     = (const float*)d_in[4];
  const float* W1     = (const float*)d_in[5];
  const float* b1     = (const float*)d_in[6];
  const float* W2     = (const float*)d_in[7];
  const float* b2     = (const float*)d_in[8];
  ushort_t* wgl = (ushort_t*)d_ws;          // ws_size >= 156448 proven round 3

  convert_weights<<<(WGL_SHORTS + 255)/256, 256, 0, stream>>>(W0,b0,W1,b1,W2,b2, wgl);
  flow_mfma<<<NROWS/64, 256, 0, stream>>>(mean, logvar, eps, wgl, (float*)d_out);
}

// Round 4
// 189.324 us; speedup vs baseline: 1.6473x; 1.0077x over previous
//
#include <hip/hip_runtime.h>

// Flow1: RealNVP coupling flow. K=32 B=4096 ZS=128 ZH=64 HS=50 NF=2.
// Round 8: fill issue slots + cut conversion VALU.
// Evidence r7: VALU-busy TIME conserved across r6->r7 (~45 us) while stalls
// halved; occupancy reads 19% (6 waves/CU) vs static cap 20 -> latency still
// unhidden. Changes:
//  (1) 128-thread blocks (2 independent waves; zero barriers anyway).
//      LDS/block 9216 B -> up to 16-17 blocks/CU granularity, finer
//      scheduling; grid 4096.
//  (2) f2bf via hardware bf16 cast (__bf16, 1 v_cvt) instead of 4-op manual
//      RNE -- ~20% of VALU stream (32 conversions/lane/step).
//  - Weights read straight from global (L1/L2-resident, 110 KB total).
//  - Zero barriers: zA/hA per-wave; same-wave DS ordering carries hazards.
//
// Layouts (m89/m91-verified):
//   A-frag: A[m][k], m=lane&15, k=quad*8+j (j=0..7) per 32-K-tile
//   B-frag: B[k][n], n=lane&15, k=quad*8+j
//   C/D   : D[m][n], n=lane&15, m=quad*4+reg

typedef unsigned short ushort_t;
typedef unsigned int   uint_t;
typedef short bf8 __attribute__((ext_vector_type(8)));
typedef float f4  __attribute__((ext_vector_type(4)));

#define KK   32
#define BB   4096
#define ZSD  128
#define ZHD  64
#define HSD  50
#define NROWS (KK*BB)

#define WST  72                   // k-stride (shorts) for weight/act tiles
#define MATS (64*WST)             // shorts per padded matrix  = 4608
#define WGL_SHORTS (12*MATS)      // 55296 shorts = 110592 B
#define WS_BYTES   (WGL_SHORTS*2 + 768*4)   // + padded fp32 biases [4][3][64]

__device__ __forceinline__ float bf2f(ushort_t u){ union{uint_t i; float f;} v; v.i = ((uint_t)u)<<16; return v.f; }

// hardware bf16 convert (RNE on gfx950); compiler packs/schedules it
__device__ __forceinline__ ushort_t f2bf(float f){
  union{__bf16 h; ushort_t u;} v; v.h = (__bf16)f; return v.u;
}

__device__ __forceinline__ float rcp_fast(float x){ return __builtin_amdgcn_rcpf(x); }

__device__ __forceinline__ float tanh_fast(float x){
  float ax = fabsf(x);
  float t  = __expf(-2.0f*ax);                  // (0,1]
  float r  = (1.0f - t) * rcp_fast(1.0f + t);
  union{float f; uint_t i;} u, s; u.f = r; s.f = x;
  u.i |= (s.i & 0x80000000u);
  return u.f;
}

__device__ __forceinline__ void sigmoid_log(float x, float& sig, float& lsig){
  float ax  = fabsf(x);
  float e   = __expf(-ax);
  float d   = 1.0f + e;
  float inv = rcp_fast(d);
  float ld  = __logf(d);
  bool pos  = (x >= 0.0f);
  sig  = pos ? inv : e*inv;
  lsig = pos ? -ld : x - ld;
}

__device__ __forceinline__ f4 MFMA(bf8 a, bf8 b, f4 c){
  return __builtin_amdgcn_mfma_f32_16x16x32_bf16(a, b, c, 0, 0, 0);
}

// ---- weight preconversion: fp32 -> padded bf16 [step][mat][n][WST] + biases
__global__ void convert_weights(const float* __restrict__ W0g,
                                const float* __restrict__ b0g,
                                const float* __restrict__ W1g,
                                const float* __restrict__ b1g,
                                const float* __restrict__ W2g,
                                const float* __restrict__ b2g,
                                ushort_t* __restrict__ wgl)
{
  int t = blockIdx.x*256 + threadIdx.x;
  if (t < WGL_SHORTS){
    int mi  = t / MATS;             // step*3 + which
    int rem = t % MATS;
    int n   = rem / WST;
    int k   = rem % WST;
    int step  = mi / 3;
    int which = mi % 3;
    float v = 0.0f;
    if (which == 0){                           // B0[k=z][n=h] = W0[step][n][k]
      if (n < HSD && k < ZHD) v = W0g[(step*HSD + n)*ZHD + k];
    } else if (which == 1){                    // B1[k=h][n=z] = W1[step][n][k]
      if (k < HSD)            v = W1g[(step*ZHD + n)*HSD + k];
    } else {
      if (k < HSD)            v = W2g[(step*ZHD + n)*HSD + k];
    }
    wgl[t] = f2bf(v);
  }
  if (t < 768){                                // biases fp32 padded to 64
    float* bp = (float*)(wgl + WGL_SHORTS);
    int step  = t / 192;
    int rem   = t % 192;
    int which = rem / 64;
    int n     = rem % 64;
    float v = 0.0f;
    if (which == 0){ if (n < HSD) v = b0g[step*HSD + n]; }
    else if (which == 1) v = b1g[step*ZHD + n];
    else                 v = b2g[step*ZHD + n];
    bp[t] = v;
  }
}

// one coupling step; pz = passive-half registers (updated), active already in zAw
__device__ __forceinline__ void do_step(
    int s, float (&pz)[16], float (&T)[4],
    ushort_t* zAw, ushort_t* hAw,
    const ushort_t* wgl, const float* wsb,
    int quad, int l15, int wr)
{
  // this step's 3 matrices, read directly from global (L1/L2-resident)
  const ushort_t* ws = wgl + (size_t)(s*3)*MATS;

  // ---- phase A: H = tanh(Zact @ B0 + b0) ----
  bf8 zf[2];
  #pragma unroll
  for (int kt=0;kt<2;++kt)
    zf[kt] = *(const bf8*)(zAw + l15*WST + kt*32 + quad*8);

  #pragma unroll
  for (int nt=0;nt<4;++nt){
    const ushort_t* wb = ws + (0*64 + nt*16 + l15)*WST + quad*8;
    bf8 w0a = *(const bf8*)(wb);
    bf8 w0b = *(const bf8*)(wb + 32);
    float b0v = wsb[(s*3+0)*64 + nt*16 + l15];
    f4 acc = {0.f,0.f,0.f,0.f};
    acc = MFMA(zf[0], w0a, acc);
    acc = MFMA(zf[1], w0b, acc);
    #pragma unroll
    for (int i=0;i<4;++i){
      float h = tanh_fast(acc[i] + b0v);
      hAw[(quad*4 + i)*WST + nt*16 + l15] = f2bf(h);
    }
  }

  // ---- phase B: MEW = H@B1 + b1 ; SIG = sigmoid(H@B2 + b2) ----
  bf8 hf[2];
  #pragma unroll
  for (int kt=0;kt<2;++kt)
    hf[kt] = *(const bf8*)(hAw + l15*WST + kt*32 + quad*8);

  #pragma unroll
  for (int nt=0;nt<4;++nt){
    const ushort_t* w1p = ws + (1*64 + nt*16 + l15)*WST + quad*8;
    const ushort_t* w2p = ws + (2*64 + nt*16 + l15)*WST + quad*8;
    bf8 w1a = *(const bf8*)(w1p);
    bf8 w1b = *(const bf8*)(w1p + 32);
    bf8 w2a = *(const bf8*)(w2p);
    bf8 w2b = *(const bf8*)(w2p + 32);
    float b1v = wsb[(s*3+1)*64 + nt*16 + l15];
    float b2v = wsb[(s*3+2)*64 + nt*16 + l15];
    f4 am = {0.f,0.f,0.f,0.f};
    f4 as = {0.f,0.f,0.f,0.f};
    am = MFMA(hf[0], w1a, am);
    am = MFMA(hf[1], w1b, am);
    as = MFMA(hf[0], w2a, as);
    as = MFMA(hf[1], w2b, as);
    #pragma unroll
    for (int i=0;i<4;++i){
      float mew  = am[i] + b1v;
      float spre = as[i] + b2v;
      float sig, lsig;
      sigmoid_log(spre, sig, lsig);
      pz[nt*4+i] = fmaf(pz[nt*4+i], sig, mew);
      T[i] += lsig;
    }
  }

  // new active = just-updated passive -> zA (bf16, A-layout)
  if (wr){
    #pragma unroll
    for (int nt=0;nt<4;++nt)
      #pragma unroll
      for (int i=0;i<4;++i)
        zAw[(quad*4 + i)*WST + nt*16 + l15] = f2bf(pz[nt*4+i]);
  }
}

__global__ __launch_bounds__(128) void flow_mfma(
    const float* __restrict__ mean, const float* __restrict__ logvar,
    const float* __restrict__ eps,
    const ushort_t* __restrict__ wgl,
    float* __restrict__ out)
{
  __shared__ __align__(16) ushort_t zA[2][16*WST];      // 2 x 2304 B
  __shared__ __align__(16) ushort_t hA[2][16*WST];      // 2 x 2304 B

  const int tid  = threadIdx.x;
  const int wave = tid >> 6;
  const int lane = tid & 63;
  const int quad = lane >> 4;
  const int l15  = lane & 15;
  const int rbase = blockIdx.x*32 + wave*16;

  const float* wsb = (const float*)(wgl + WGL_SHORTS);
  ushort_t* zAw = zA[wave];
  ushort_t* hAw = hA[wave];

  // z1D/z2D in C/D layout: [nt*4+reg] -> row=quad*4+reg,
  // col(z-index within half)=nt*16+l15
  float z1D[16], z2D[16];
  float T[4];                        // T = 0.5*sum(lv+eps^2) + sum(lsig)

  // ---- init: z = eps*exp(0.5*lv)+mean, loaded directly in D-layout ----
  #pragma unroll
  for (int i=0;i<4;++i){
    int rrow = rbase + quad*4 + i;
    int brow = rrow & (BB-1);
    const float* er = eps    + (size_t)rrow*ZSD;
    const float* mr = mean   + (size_t)brow*ZSD;
    const float* vr = logvar + (size_t)brow*ZSD;
    float acc = 0.f;
    #pragma unroll
    for (int nt=0;nt<4;++nt){
      int c1 = nt*16 + l15;
      int c2 = 64 + c1;
      float e1 = er[c1], v1 = vr[c1], m1 = mr[c1];
      float e2 = er[c2], v2 = vr[c2], m2 = mr[c2];
      z1D[nt*4+i] = fmaf(e1, __expf(0.5f*v1), m1);
      z2D[nt*4+i] = fmaf(e2, __expf(0.5f*v2), m2);
      acc += (v1 + e1*e1) + (v2 + e2*e2);
    }
    T[i] = 0.5f*acc;
  }

  // initial active = z1 -> zA
  #pragma unroll
  for (int nt=0;nt<4;++nt)
    #pragma unroll
    for (int i=0;i<4;++i)
      zAw[(quad*4 + i)*WST + nt*16 + l15] = f2bf(z1D[nt*4+i]);

  // ---- 4 coupling steps (2 bodies in a non-unrolled loop to bound I$) ----
  #pragma unroll 1
  for (int it=0; it<2; ++it){
    do_step(2*it+0, z2D, T, zAw, hAw, wgl, wsb, quad, l15, 1);
    do_step(2*it+1, z1D, T, zAw, hAw, wgl, wsb, quad, l15, it==0);
  }

  // ---- store z_out (fp32) ----
  #pragma unroll
  for (int i=0;i<4;++i){
    int rrow = rbase + quad*4 + i;
    float* orow = out + (size_t)rrow*ZSD;
    #pragma unroll
    for (int nt=0;nt<4;++nt){
      orow[nt*16 + l15]      = z1D[nt*4+i];
      orow[64 + nt*16 + l15] = z2D[nt*4+i];
    }
  }

  // ---- logpz = -0.5*128*ln(2pi) - T_rowsum ; reduce T across the 16 lanes
  // of each quad (they cover all 128 cols of rows quad*4+reg) ----
  #pragma unroll
  for (int i=0;i<4;++i){
    float v = T[i];
    v += __shfl_xor(v, 1, 64);
    v += __shfl_xor(v, 2, 64);
    v += __shfl_xor(v, 4, 64);
    v += __shfl_xor(v, 8, 64);
    T[i] = v;
  }
  if (l15 == 0){
    const float NC = -0.5f * 128.0f * 1.8378770664093453f;
    #pragma unroll
    for (int i=0;i<4;++i){
      int rrow = rbase + quad*4 + i;
      out[(size_t)NROWS*ZSD + rrow] = NC - T[i];
    }
  }
}

extern "C" void kernel_launch(void* const* d_in, const int* in_sizes, int n_in,
                              void* d_out, int out_size, void* d_ws, size_t ws_size,
                              hipStream_t stream)
{
  const float* mean   = (const float*)d_in[0];
  const float* logvar = (const float*)d_in[1];
  const float* eps    = (const float*)d_in[2];
  const float* W0     = (const float*)d_in[3];
  const float* b0     = (const float*)d_in[4];
  const float* W1     = (const float*)d_in[5];
  const float* b1     = (const float*)d_in[6];
  const float* W2     = (const float*)d_in[7];
  const float* b2     = (const float*)d_in[8];
  ushort_t* wgl = (ushort_t*)d_ws;          // ws_size >= 156448 proven round 3

  convert_weights<<<(WGL_SHORTS + 255)/256, 256, 0, stream>>>(W0,b0,W1,b1,W2,b2, wgl);
  flow_mfma<<<NROWS/32, 128, 0, stream>>>(mean, logvar, eps, wgl, (float*)d_out);
}

// Round 5
// 174.828 us; speedup vs baseline: 1.7839x; 1.0829x over previous
//
#include <hip/hip_runtime.h>

// Flow1: RealNVP coupling flow. K=32 B=4096 ZS=128 ZH=64 HS=50 NF=2.
// Round 9: in-wave ILP + trans-pipe diet.
// Evidence r8: occupancy pinned ~6 waves/CU regardless of block shape/LDS;
// wave lifetime 16us vs ~3us issue work -> serial-chain latency-bound and
// TLP won't rise. Fixes:
//  (1) 2 independent M-tiles per wave (32 rows), restoring r6 structure but
//      WITHOUT launch_bounds min-waves (r6's 84-VGPR spill was the bounds
//      pathology, not the 2-tile idea). Weight frags shared by both tiles.
//      While tile A stalls (ds/L2/trans), tile B issues. ~150-170 VGPR, no
//      spill expected. Tripwire: WRITE_SIZE >70MB => spill came back.
//  (2) logdet via per-step product-of-sigmoids, ONE __logf per acc per step:
//      v_log count 256 -> 32 per lane (+removes 2 VALU/elem select+add).
//      Safe: |spre| <= ~7.2 (h in (-1,1), |W2| <= 0.1414, 50 terms) =>
//      4-sig product >= 2e-13, no underflow.
//  - Weights read straight from global (L1/L2-resident, 110 KB total).
//  - Zero barriers: zA/hA per-wave; same-wave DS ordering carries hazards.
//
// Layouts (m89/m91-verified):
//   A-frag: A[m][k], m=lane&15, k=quad*8+j (j=0..7) per 32-K-tile
//   B-frag: B[k][n], n=lane&15, k=quad*8+j
//   C/D   : D[m][n], n=lane&15, m=quad*4+reg

typedef unsigned short ushort_t;
typedef unsigned int   uint_t;
typedef short bf8 __attribute__((ext_vector_type(8)));
typedef float f4  __attribute__((ext_vector_type(4)));

#define KK   32
#define BB   4096
#define ZSD  128
#define ZHD  64
#define HSD  50
#define NROWS (KK*BB)

#define WST  72                   // k-stride (shorts) for weight/act tiles
#define MATS (64*WST)             // shorts per padded matrix  = 4608
#define WGL_SHORTS (12*MATS)      // 55296 shorts = 110592 B
#define WS_BYTES   (WGL_SHORTS*2 + 768*4)   // + padded fp32 biases [4][3][64]

__device__ __forceinline__ float bf2f(ushort_t u){ union{uint_t i; float f;} v; v.i = ((uint_t)u)<<16; return v.f; }

// hardware bf16 convert (RNE on gfx950)
__device__ __forceinline__ ushort_t f2bf(float f){
  union{__bf16 h; ushort_t u;} v; v.h = (__bf16)f; return v.u;
}

__device__ __forceinline__ float rcp_fast(float x){ return __builtin_amdgcn_rcpf(x); }

__device__ __forceinline__ float tanh_fast(float x){
  float ax = fabsf(x);
  float t  = __expf(-2.0f*ax);                  // (0,1]
  float r  = (1.0f - t) * rcp_fast(1.0f + t);
  union{float f; uint_t i;} u, s; u.f = r; s.f = x;
  u.i |= (s.i & 0x80000000u);
  return u.f;
}

// sigmoid only (log handled via product accumulation outside)
__device__ __forceinline__ float sigmoid_fast(float x){
  float ax  = fabsf(x);
  float e   = __expf(-ax);
  float inv = rcp_fast(1.0f + e);
  return (x >= 0.0f) ? inv : e*inv;
}

__device__ __forceinline__ f4 MFMA(bf8 a, bf8 b, f4 c){
  return __builtin_amdgcn_mfma_f32_16x16x32_bf16(a, b, c, 0, 0, 0);
}

// ---- weight preconversion: fp32 -> padded bf16 [step][mat][n][WST] + biases
__global__ void convert_weights(const float* __restrict__ W0g,
                                const float* __restrict__ b0g,
                                const float* __restrict__ W1g,
                                const float* __restrict__ b1g,
                                const float* __restrict__ W2g,
                                const float* __restrict__ b2g,
                                ushort_t* __restrict__ wgl)
{
  int t = blockIdx.x*256 + threadIdx.x;
  if (t < WGL_SHORTS){
    int mi  = t / MATS;             // step*3 + which
    int rem = t % MATS;
    int n   = rem / WST;
    int k   = rem % WST;
    int step  = mi / 3;
    int which = mi % 3;
    float v = 0.0f;
    if (which == 0){                           // B0[k=z][n=h] = W0[step][n][k]
      if (n < HSD && k < ZHD) v = W0g[(step*HSD + n)*ZHD + k];
    } else if (which == 1){                    // B1[k=h][n=z] = W1[step][n][k]
      if (k < HSD)            v = W1g[(step*ZHD + n)*HSD + k];
    } else {
      if (k < HSD)            v = W2g[(step*ZHD + n)*HSD + k];
    }
    wgl[t] = f2bf(v);
  }
  if (t < 768){                                // biases fp32 padded to 64
    float* bp = (float*)(wgl + WGL_SHORTS);
    int step  = t / 192;
    int rem   = t % 192;
    int which = rem / 64;
    int n     = rem % 64;
    float v = 0.0f;
    if (which == 0){ if (n < HSD) v = b0g[step*HSD + n]; }
    else if (which == 1) v = b1g[step*ZHD + n];
    else                 v = b2g[step*ZHD + n];
    bp[t] = v;
  }
}

// one coupling step; pz = passive-half registers (2 M-tiles, updated),
// active halves already in zAw
__device__ __forceinline__ void do_step(
    int s, float (&pz)[2][16], float (&T)[2][4],
    ushort_t* zAw, ushort_t* hAw,
    const ushort_t* wgl, const float* wsb,
    int quad, int l15, int wr)
{
  // this step's 3 matrices, read directly from global (L1/L2-resident)
  const ushort_t* ws = wgl + (size_t)(s*3)*MATS;

  // ---- phase A: H = tanh(Zact @ B0 + b0) ----
  bf8 zf[2][2];
  #pragma unroll
  for (int m=0;m<2;++m)
    #pragma unroll
    for (int kt=0;kt<2;++kt)
      zf[m][kt] = *(const bf8*)(zAw + (m*16 + l15)*WST + kt*32 + quad*8);

  #pragma unroll
  for (int nt=0;nt<4;++nt){
    const ushort_t* wb = ws + (0*64 + nt*16 + l15)*WST + quad*8;
    bf8 w0a = *(const bf8*)(wb);
    bf8 w0b = *(const bf8*)(wb + 32);
    float b0v = wsb[(s*3+0)*64 + nt*16 + l15];
    #pragma unroll
    for (int m=0;m<2;++m){
      f4 acc = {0.f,0.f,0.f,0.f};
      acc = MFMA(zf[m][0], w0a, acc);
      acc = MFMA(zf[m][1], w0b, acc);
      #pragma unroll
      for (int i=0;i<4;++i){
        float h = tanh_fast(acc[i] + b0v);
        hAw[(m*16 + quad*4 + i)*WST + nt*16 + l15] = f2bf(h);
      }
    }
  }

  // ---- phase B: MEW = H@B1 + b1 ; SIG = sigmoid(H@B2 + b2) ----
  bf8 hf[2][2];
  #pragma unroll
  for (int m=0;m<2;++m)
    #pragma unroll
    for (int kt=0;kt<2;++kt)
      hf[m][kt] = *(const bf8*)(hAw + (m*16 + l15)*WST + kt*32 + quad*8);

  // product-of-sigmoids accumulators: one log per (m,i) per step
  float sp[2][4];
  #pragma unroll
  for (int m=0;m<2;++m)
    #pragma unroll
    for (int i=0;i<4;++i) sp[m][i] = 1.0f;

  #pragma unroll
  for (int nt=0;nt<4;++nt){
    const ushort_t* w1p = ws + (1*64 + nt*16 + l15)*WST + quad*8;
    const ushort_t* w2p = ws + (2*64 + nt*16 + l15)*WST + quad*8;
    bf8 w1a = *(const bf8*)(w1p);
    bf8 w1b = *(const bf8*)(w1p + 32);
    bf8 w2a = *(const bf8*)(w2p);
    bf8 w2b = *(const bf8*)(w2p + 32);
    float b1v = wsb[(s*3+1)*64 + nt*16 + l15];
    float b2v = wsb[(s*3+2)*64 + nt*16 + l15];
    #pragma unroll
    for (int m=0;m<2;++m){
      f4 am = {0.f,0.f,0.f,0.f};
      f4 as = {0.f,0.f,0.f,0.f};
      am = MFMA(hf[m][0], w1a, am);
      am = MFMA(hf[m][1], w1b, am);
      as = MFMA(hf[m][0], w2a, as);
      as = MFMA(hf[m][1], w2b, as);
      #pragma unroll
      for (int i=0;i<4;++i){
        float mew  = am[i] + b1v;
        float spre = as[i] + b2v;
        float sig  = sigmoid_fast(spre);
        sp[m][i] *= sig;
        pz[m][nt*4+i] = fmaf(pz[m][nt*4+i], sig, mew);
      }
    }
  }

  #pragma unroll
  for (int m=0;m<2;++m)
    #pragma unroll
    for (int i=0;i<4;++i)
      T[m][i] += __logf(sp[m][i]);    // sum of log(sig) over this step's 4 nt

  // new active = just-updated passive -> zA (bf16, A-layout)
  if (wr){
    #pragma unroll
    for (int m=0;m<2;++m)
      #pragma unroll
      for (int nt=0;nt<4;++nt)
        #pragma unroll
        for (int i=0;i<4;++i)
          zAw[(m*16 + quad*4 + i)*WST + nt*16 + l15] = f2bf(pz[m][nt*4+i]);
  }
}

__global__ __launch_bounds__(128) void flow_mfma(
    const float* __restrict__ mean, const float* __restrict__ logvar,
    const float* __restrict__ eps,
    const ushort_t* __restrict__ wgl,
    float* __restrict__ out)
{
  __shared__ __align__(16) ushort_t zA[2][32*WST];      // 2 x 4608 B
  __shared__ __align__(16) ushort_t hA[2][32*WST];      // 2 x 4608 B

  const int tid  = threadIdx.x;
  const int wave = tid >> 6;
  const int lane = tid & 63;
  const int quad = lane >> 4;
  const int l15  = lane & 15;
  const int rbase = blockIdx.x*64 + wave*32;

  const float* wsb = (const float*)(wgl + WGL_SHORTS);
  ushort_t* zAw = zA[wave];
  ushort_t* hAw = hA[wave];

  // z1D/z2D in C/D layout: [mtile][nt*4+reg] -> row=mtile*16+quad*4+reg,
  // col(z-index within half)=nt*16+l15
  float z1D[2][16], z2D[2][16];
  float T[2][4];                     // T = 0.5*sum(lv+eps^2) + sum(lsig)

  // ---- init: z = eps*exp(0.5*lv)+mean, loaded directly in D-layout ----
  #pragma unroll
  for (int m=0;m<2;++m){
    #pragma unroll
    for (int i=0;i<4;++i){
      int rrow = rbase + m*16 + quad*4 + i;
      int brow = rrow & (BB-1);
      const float* er = eps    + (size_t)rrow*ZSD;
      const float* mr = mean   + (size_t)brow*ZSD;
      const float* vr = logvar + (size_t)brow*ZSD;
      float acc = 0.f;
      #pragma unroll
      for (int nt=0;nt<4;++nt){
        int c1 = nt*16 + l15;
        int c2 = 64 + c1;
        float e1 = er[c1], v1 = vr[c1], m1 = mr[c1];
        float e2 = er[c2], v2 = vr[c2], m2 = mr[c2];
        z1D[m][nt*4+i] = fmaf(e1, __expf(0.5f*v1), m1);
        z2D[m][nt*4+i] = fmaf(e2, __expf(0.5f*v2), m2);
        acc += (v1 + e1*e1) + (v2 + e2*e2);
      }
      T[m][i] = 0.5f*acc;
    }
  }

  // initial active = z1 -> zA
  #pragma unroll
  for (int m=0;m<2;++m)
    #pragma unroll
    for (int nt=0;nt<4;++nt)
      #pragma unroll
      for (int i=0;i<4;++i)
        zAw[(m*16 + quad*4 + i)*WST + nt*16 + l15] = f2bf(z1D[m][nt*4+i]);

  // ---- 4 coupling steps (2 bodies in a non-unrolled loop to bound I$) ----
  #pragma unroll 1
  for (int it=0; it<2; ++it){
    do_step(2*it+0, z2D, T, zAw, hAw, wgl, wsb, quad, l15, 1);
    do_step(2*it+1, z1D, T, zAw, hAw, wgl, wsb, quad, l15, it==0);
  }

  // ---- store z_out (fp32) ----
  #pragma unroll
  for (int m=0;m<2;++m){
    #pragma unroll
    for (int i=0;i<4;++i){
      int rrow = rbase + m*16 + quad*4 + i;
      float* orow = out + (size_t)rrow*ZSD;
      #pragma unroll
      for (int nt=0;nt<4;++nt){
        orow[nt*16 + l15]      = z1D[m][nt*4+i];
        orow[64 + nt*16 + l15] = z2D[m][nt*4+i];
      }
    }
  }

  // ---- logpz = -0.5*128*ln(2pi) - T_rowsum ; reduce T across the 16 lanes
  // of each quad (they cover all 128 cols of rows quad*4+reg) ----
  #pragma unroll
  for (int m=0;m<2;++m)
    #pragma unroll
    for (int i=0;i<4;++i){
      float v = T[m][i];
      v += __shfl_xor(v, 1, 64);
      v += __shfl_xor(v, 2, 64);
      v += __shfl_xor(v, 4, 64);
      v += __shfl_xor(v, 8, 64);
      T[m][i] = v;
    }
  if (l15 == 0){
    const float NC = -0.5f * 128.0f * 1.8378770664093453f;
    #pragma unroll
    for (int m=0;m<2;++m)
      #pragma unroll
      for (int i=0;i<4;++i){
        int rrow = rbase + m*16 + quad*4 + i;
        out[(size_t)NROWS*ZSD + rrow] = NC - T[m][i];
      }
  }
}

extern "C" void kernel_launch(void* const* d_in, const int* in_sizes, int n_in,
                              void* d_out, int out_size, void* d_ws, size_t ws_size,
                              hipStream_t stream)
{
  const float* mean   = (const float*)d_in[0];
  const float* logvar = (const float*)d_in[1];
  const float* eps    = (const float*)d_in[2];
  const float* W0     = (const float*)d_in[3];
  const float* b0     = (const float*)d_in[4];
  const float* W1     = (const float*)d_in[5];
  const float* b1     = (const float*)d_in[6];
  const float* W2     = (const float*)d_in[7];
  const float* b2     = (const float*)d_in[8];
  ushort_t* wgl = (ushort_t*)d_ws;          // ws_size >= 156448 proven round 3

  convert_weights<<<(WGL_SHORTS + 255)/256, 256, 0, stream>>>(W0,b0,W1,b1,W2,b2, wgl);
  flow_mfma<<<NROWS/64, 128, 0, stream>>>(mean, logvar, eps, wgl, (float*)d_out);
}